// Round 4
// baseline (1208.219 us; speedup 1.0000x reference)
//
#include <hip/hip_runtime.h>
#include <stdint.h>

// ---------------- problem constants ----------------
#define NFRAMES 2
#define NPROP   16384
#define NROWS   (NFRAMES * NPROP)        // 32768
#define DIN_    1024
#define HDIM    512
#define NCLS    11
#define LRLD    128                      // padded cols of [logits(11) | reg(99) | pad]
#define NBINS   8192
#define CAP     4096                     // gathered candidate capacity per frame
#define TGT     1024                     // target top-N for NMS scan
#define KKEEP   100
#define SCORE_T 0.05f
#define NMS_T   0.5f
#define CLIPV   4.135166556742356f       // log(1000/16)
#define BK      8

// ---------------- workspace layout (bytes) ----------------
#define OFF_H1      0ULL                           // 32768*512 f32
#define OFF_H2      67108864ULL                    // 32768*512 f32
#define OFF_LR      134217728ULL                   // 32768*128 f32
#define OFF_WCAT    150994944ULL                   // 512*128 f32
#define OFF_BCAT    151257088ULL                   // 128 f32 (padded)
#define OFF_SCORES  151258112ULL                   // 32768*10 f32
#define OFF_HIST    152568832ULL                   // 2*8192 i32
#define OFF_GCNT    152634368ULL                   // 2 i32
#define OFF_TAU     152634376ULL                   // 2 i32
#define OFF_GKEYS   152634624ULL                   // 2*4096 u64
#define WS_NEEDED   152700160ULL

// ---------------- box decode (must match reference float ops) ----------------
__device__ __forceinline__ void decode4(const float* __restrict__ prop,
                                        const float* __restrict__ rg,
                                        float& x1, float& y1, float& x2, float& y2) {
    float w  = prop[2] - prop[0];
    float h  = prop[3] - prop[1];
    float cx = prop[0] + 0.5f * w;
    float cy = prop[1] + 0.5f * h;
    float dx = rg[0] / 10.0f;
    float dy = rg[1] / 10.0f;
    float dw = fminf(rg[2] / 5.0f, CLIPV);
    float dh = fminf(rg[3] / 5.0f, CLIPV);
    float pcx = dx * w + cx;
    float pcy = dy * h + cy;
    float pw  = expf(dw) * w;
    float ph  = expf(dh) * h;
    x1 = pcx - 0.5f * pw;
    y1 = pcy - 0.5f * ph;
    x2 = pcx + 0.5f * pw;
    y2 = pcy + 0.5f * ph;
}

// ---------------- fp32 GEMM, 256x128 tile, TM=16 x TN=8 ----------------
// R3: the 8x8 micro-tile is LDS-BW-bound (4 b128 reads / 64 FMA = 1 B/FMA ->
// VALUBusy capped at 128/192 = 66%, matches R1/R2 measurements). 16x8 gives
// 6 b128 / 128 FMA -> 0.75 B/FMA -> predicted ~89% VALU util.
// Single LDS buffer (12 KB), 2 barriers/stage (R1's proven structure), register
// prefetch of next stage issued before the compute stage.
__global__ __launch_bounds__(256, 2) void gemm_t16(const float* __restrict__ A,
                                                   const float* __restrict__ B,
                                                   const float* __restrict__ bias,
                                                   float* __restrict__ C,
                                                   int K, int N, int do_relu) {
    __shared__ float As[BK][256];   // k-major, 8 KB
    __shared__ float Bs[BK][128];   // 4 KB
    const int tid  = threadIdx.x;
    const int row0 = blockIdx.x * 256;
    const int col0 = blockIdx.y * 128;
    const int tx4  = (tid & 15) * 4;        // col offsets tx4 and 64+tx4
    const int rg16 = (tid >> 4) * 16;       // 16 consecutive rows

    // staging: A -> thread loads row (row0+tid), 8 k-floats; B -> one float4
    const int bkr = tid >> 5;               // 0..7
    const int bc4 = (tid & 31) * 4;         // 0..124
    const float* Ap = A + (size_t)(row0 + tid) * K;
    const float* Bp = B + (size_t)bkr * N + col0 + bc4;

    float acc[16][8];
#pragma unroll
    for (int i = 0; i < 16; ++i)
#pragma unroll
        for (int j = 0; j < 8; ++j) acc[i][j] = 0.f;

    // prologue: stage 0
    float4 pa0 = *(const float4*)(Ap + 0);
    float4 pa1 = *(const float4*)(Ap + 4);
    float4 pb  = *(const float4*)(Bp);
    As[0][tid] = pa0.x; As[1][tid] = pa0.y; As[2][tid] = pa0.z; As[3][tid] = pa0.w;
    As[4][tid] = pa1.x; As[5][tid] = pa1.y; As[6][tid] = pa1.z; As[7][tid] = pa1.w;
    *(float4*)&Bs[bkr][bc4] = pb;
    __syncthreads();

    for (int k0 = 0; k0 < K; k0 += BK) {
        const bool has_next = (k0 + BK) < K;
        if (has_next) {   // prefetch next stage; consumed after 8*128 FMAs
            pa0 = *(const float4*)(Ap + k0 + BK);
            pa1 = *(const float4*)(Ap + k0 + BK + 4);
            pb  = *(const float4*)(Bp + (size_t)(k0 + BK) * N);
        }
#pragma unroll
        for (int kk = 0; kk < BK; ++kk) {
            float4 a0 = *(const float4*)&As[kk][rg16 + 0];
            float4 a1 = *(const float4*)&As[kk][rg16 + 4];
            float4 a2 = *(const float4*)&As[kk][rg16 + 8];
            float4 a3 = *(const float4*)&As[kk][rg16 + 12];
            float4 b0 = *(const float4*)&Bs[kk][tx4];
            float4 b1 = *(const float4*)&Bs[kk][64 + tx4];
            float ar[16] = {a0.x, a0.y, a0.z, a0.w, a1.x, a1.y, a1.z, a1.w,
                            a2.x, a2.y, a2.z, a2.w, a3.x, a3.y, a3.z, a3.w};
            float br[8]  = {b0.x, b0.y, b0.z, b0.w, b1.x, b1.y, b1.z, b1.w};
#pragma unroll
            for (int i = 0; i < 16; ++i)
#pragma unroll
                for (int j = 0; j < 8; ++j) acc[i][j] += ar[i] * br[j];
        }
        if (has_next) {
            __syncthreads();   // all reads of current buffer done
            As[0][tid] = pa0.x; As[1][tid] = pa0.y; As[2][tid] = pa0.z; As[3][tid] = pa0.w;
            As[4][tid] = pa1.x; As[5][tid] = pa1.y; As[6][tid] = pa1.z; As[7][tid] = pa1.w;
            *(float4*)&Bs[bkr][bc4] = pb;
            __syncthreads();   // writes visible
        }
    }

    float4 bias_lo = *(const float4*)&bias[col0 + tx4];
    float4 bias_hi = *(const float4*)&bias[col0 + 64 + tx4];
#pragma unroll
    for (int i = 0; i < 16; ++i) {
        int row = row0 + rg16 + i;
        float4 v;
        v.x = acc[i][0] + bias_lo.x; v.y = acc[i][1] + bias_lo.y;
        v.z = acc[i][2] + bias_lo.z; v.w = acc[i][3] + bias_lo.w;
        if (do_relu) {
            v.x = fmaxf(v.x, 0.f); v.y = fmaxf(v.y, 0.f);
            v.z = fmaxf(v.z, 0.f); v.w = fmaxf(v.w, 0.f);
        }
        *(float4*)(C + (size_t)row * N + col0 + tx4) = v;
        v.x = acc[i][4] + bias_hi.x; v.y = acc[i][5] + bias_hi.y;
        v.z = acc[i][6] + bias_hi.z; v.w = acc[i][7] + bias_hi.w;
        if (do_relu) {
            v.x = fmaxf(v.x, 0.f); v.y = fmaxf(v.y, 0.f);
            v.z = fmaxf(v.z, 0.f); v.w = fmaxf(v.w, 0.f);
        }
        *(float4*)(C + (size_t)row * N + col0 + 64 + tx4) = v;
    }
}

// ---------------- fp32 GEMM 128x128, 8x8/thread (R1 version, for gemm3 N=128) ----------------
__global__ __launch_bounds__(256) void gemm128(const float* __restrict__ A,
                                               const float* __restrict__ B,
                                               const float* __restrict__ bias,
                                               float* __restrict__ C,
                                               int K, int N, int do_relu) {
    __shared__ float As[8][128];
    __shared__ float Bs[8][128];
    const int tid  = threadIdx.x;
    const int row0 = blockIdx.x * 128;
    const int col0 = blockIdx.y * 128;
    const int tx = tid & 15, ty = tid >> 4;

    float acc[8][8];
#pragma unroll
    for (int i = 0; i < 8; ++i)
#pragma unroll
        for (int j = 0; j < 8; ++j) acc[i][j] = 0.f;

    const int arow  = tid >> 1;
    const int akoff = (tid & 1) * 4;
    const int bkrow = tid >> 5;
    const int bcol  = (tid & 31) * 4;
    const float* Ap = A + (size_t)(row0 + arow) * K + akoff;
    const float* Bp = B + (size_t)bkrow * N + col0 + bcol;

    for (int k0 = 0; k0 < K; k0 += 8) {
        float4 av = *(const float4*)(Ap + k0);
        float4 bv = *(const float4*)(Bp + (size_t)k0 * N);
        __syncthreads();
        As[akoff + 0][arow] = av.x;
        As[akoff + 1][arow] = av.y;
        As[akoff + 2][arow] = av.z;
        As[akoff + 3][arow] = av.w;
        *(float4*)&Bs[bkrow][bcol] = bv;
        __syncthreads();
#pragma unroll
        for (int kk = 0; kk < 8; ++kk) {
            float4 a0 = *(const float4*)&As[kk][ty * 4];
            float4 a1 = *(const float4*)&As[kk][64 + ty * 4];
            float4 b0 = *(const float4*)&Bs[kk][tx * 4];
            float4 b1 = *(const float4*)&Bs[kk][64 + tx * 4];
            float ar[8] = {a0.x, a0.y, a0.z, a0.w, a1.x, a1.y, a1.z, a1.w};
            float br[8] = {b0.x, b0.y, b0.z, b0.w, b1.x, b1.y, b1.z, b1.w};
#pragma unroll
            for (int i = 0; i < 8; ++i)
#pragma unroll
                for (int j = 0; j < 8; ++j) acc[i][j] += ar[i] * br[j];
        }
    }

#pragma unroll
    for (int qi = 0; qi < 2; ++qi)
#pragma unroll
        for (int i = 0; i < 4; ++i) {
            int row = row0 + qi * 64 + ty * 4 + i;
#pragma unroll
            for (int qj = 0; qj < 2; ++qj) {
                int col = col0 + qj * 64 + tx * 4;
                float4 v;
                v.x = acc[qi * 4 + i][qj * 4 + 0] + bias[col + 0];
                v.y = acc[qi * 4 + i][qj * 4 + 1] + bias[col + 1];
                v.z = acc[qi * 4 + i][qj * 4 + 2] + bias[col + 2];
                v.w = acc[qi * 4 + i][qj * 4 + 3] + bias[col + 3];
                if (do_relu) {
                    v.x = fmaxf(v.x, 0.f); v.y = fmaxf(v.y, 0.f);
                    v.z = fmaxf(v.z, 0.f); v.w = fmaxf(v.w, 0.f);
                }
                *(float4*)(C + (size_t)row * N + col) = v;
            }
        }
}

// ---------------- concat wc|wr into [512][128] (zero padded), same for bias ----------------
__global__ void concat_w(const float* __restrict__ wc, const float* __restrict__ bc,
                         const float* __restrict__ wr, const float* __restrict__ br,
                         float* __restrict__ wcat, float* __restrict__ bcat) {
    int gid = blockIdx.x * 256 + threadIdx.x;
    if (gid >= HDIM * LRLD) return;
    int k = gid >> 7, j = gid & 127;
    float v = 0.f;
    if (j < 11)       v = wc[k * 11 + j];
    else if (j < 110) v = wr[k * 99 + (j - 11)];
    wcat[gid] = v;
    if (k == 0) {
        float b = 0.f;
        if (j < 11)       b = bc[j];
        else if (j < 110) b = br[j - 11];
        bcat[j] = b;
    }
}

// ---------------- softmax + score histogram ----------------
__global__ __launch_bounds__(256) void softmax_hist(const float* __restrict__ logreg,
                                                    float* __restrict__ scores,
                                                    int* __restrict__ hist) {
    __shared__ int lh[NBINS];   // 32 KB
    const int t = threadIdx.x;
    for (int i = t; i < NBINS; i += 256) lh[i] = 0;
    __syncthreads();

    const int r = blockIdx.x * 256 + t;
    const float* lr = logreg + (size_t)r * LRLD;
    float4 v0 = *(const float4*)(lr);
    float4 v1 = *(const float4*)(lr + 4);
    float4 v2 = *(const float4*)(lr + 8);
    float l[NCLS] = {v0.x, v0.y, v0.z, v0.w, v1.x, v1.y, v1.z, v1.w, v2.x, v2.y, v2.z};
    float m = l[0];
#pragma unroll
    for (int j = 1; j < NCLS; ++j) m = fmaxf(m, l[j]);
    float e[NCLS]; float s = 0.f;
#pragma unroll
    for (int j = 0; j < NCLS; ++j) { e[j] = expf(l[j] - m); s += e[j]; }
#pragma unroll
    for (int c = 1; c < NCLS; ++c) {
        float p = e[c] / s;
        scores[(size_t)r * 10 + (c - 1)] = p;
        if (p > SCORE_T) {
            int bin = (int)(p * (float)NBINS);
            bin = min(max(bin, 0), NBINS - 1);
            atomicAdd(&lh[bin], 1);
        }
    }
    __syncthreads();
    const int b = (blockIdx.x * 256) >> 14;
    for (int i = t; i < NBINS; i += 256) {
        int c = lh[i];
        if (c) atomicAdd(&hist[b * NBINS + i], c);
    }
}

// ---------------- find histogram bin threshold covering top >= TGT ----------------
__global__ __launch_bounds__(1024) void select_tau(const int* __restrict__ hist,
                                                   int* __restrict__ taubin) {
    __shared__ int seg[1024];
    __shared__ int best;
    const int b = blockIdx.x, t = threadIdx.x;
    if (t == 0) best = 0;
    const int base = t * 8;
    int loc[8];
    int s = 0;
#pragma unroll
    for (int i = 7; i >= 0; --i) {
        s += hist[b * NBINS + base + i];
        loc[i] = s;
    }
    seg[t] = s;
    __syncthreads();
    for (int off = 1; off < 1024; off <<= 1) {
        int v = (t + off < 1024) ? seg[t + off] : 0;
        __syncthreads();
        seg[t] += v;
        __syncthreads();
    }
    const int above = (t + 1 < 1024) ? seg[t + 1] : 0;
    int bmax = -1;
#pragma unroll
    for (int i = 0; i < 8; ++i) {
        if (loc[i] + above >= TGT) bmax = base + i;
    }
    if (bmax >= 0) atomicMax(&best, bmax);
    __syncthreads();
    if (t == 0) taubin[b] = best;
}

// ---------------- gather top candidates as sortable keys ----------------
__global__ void gather_cand(const float* __restrict__ scores,
                            const float* __restrict__ logreg,
                            const float* __restrict__ proposals,
                            const int* __restrict__ taubin,
                            int* __restrict__ gcount,
                            unsigned long long* __restrict__ gkeys) {
    int gid = blockIdx.x * 256 + threadIdx.x;
    if (gid >= NROWS * 10) return;
    int r  = gid / 10;
    int ci = gid - r * 10;          // class-1
    int b  = r >> 14;
    float p = scores[gid];
    int bin = (int)(p * (float)NBINS);
    bin = min(max(bin, 0), NBINS - 1);
    if (bin < taubin[b]) return;
    if (!(p > SCORE_T)) return;
    float x1, y1, x2, y2;
    decode4(proposals + (size_t)r * 9, logreg + (size_t)r * LRLD + 11 + (ci + 1) * 9,
            x1, y1, x2, y2);
    if (!((x2 - x1) >= 0.01f && (y2 - y1) >= 0.01f)) return;
    int pos = atomicAdd(&gcount[b], 1);
    if (pos < CAP) {
        unsigned int sb   = __float_as_uint(p);                 // p > 0 => order-preserving
        unsigned int cand = (unsigned)(r - b * NPROP) * 10u + (unsigned)ci;
        gkeys[(size_t)b * CAP + pos] =
            ((unsigned long long)(0xFFFFFFFFu - sb) << 32) | (unsigned long long)cand;
    }
}

// ---------------- bitonic sort of CAP keys per frame ----------------
__global__ __launch_bounds__(1024) void sort_cand(int* __restrict__ gcount,
                                                  unsigned long long* __restrict__ gkeys) {
    __shared__ unsigned long long sk[CAP];
    int b = blockIdx.x, tid = threadIdx.x;
    int gc = gcount[b]; if (gc > CAP) gc = CAP;
    for (int i = tid; i < CAP; i += 1024)
        sk[i] = (i < gc) ? gkeys[(size_t)b * CAP + i] : ~0ULL;
    __syncthreads();
    for (int k = 2; k <= CAP; k <<= 1) {
        for (int j = k >> 1; j > 0; j >>= 1) {
            for (int i = tid; i < CAP; i += 1024) {
                int ixj = i ^ j;
                if (ixj > i) {
                    bool up = ((i & k) == 0);
                    unsigned long long a = sk[i], c = sk[ixj];
                    if ((a > c) == up) { sk[i] = c; sk[ixj] = a; }
                }
            }
            __syncthreads();
        }
    }
    for (int i = tid; i < CAP; i += 1024)
        gkeys[(size_t)b * CAP + i] = sk[i];
    if (tid == 0 && gcount[b] > CAP) gcount[b] = CAP;
}

// ---------------- serial greedy NMS scan + output ----------------
#define NPRE 2048
__global__ __launch_bounds__(64) void nms_out(const unsigned long long* __restrict__ gkeys,
                                              const int* __restrict__ gcount,
                                              const float* __restrict__ scores,
                                              const float* __restrict__ logreg,
                                              const float* __restrict__ proposals,
                                              float* __restrict__ out) {
    int b = blockIdx.x, tid = threadIdx.x;
    __shared__ unsigned long long skeys[NPRE];
    __shared__ float kbox[KKEEP][4];
    __shared__ int   kcls[KKEEP];
    __shared__ int   kcand[KKEEP];
    __shared__ int   kcount;
    if (tid == 0) kcount = 0;
    int gc = min(gcount[b], CAP);
    for (int i = tid; i < NPRE; i += 64)
        if (i < gc) skeys[i] = gkeys[(size_t)b * CAP + i];
    __syncthreads();
    for (int ptr = 0; ptr < gc; ++ptr) {
        __syncthreads();
        int kc = kcount;
        if (kc >= KKEEP) break;
        unsigned long long key = (ptr < NPRE) ? skeys[ptr] : gkeys[(size_t)b * CAP + ptr];
        unsigned int cand = (unsigned int)(key & 0xFFFFFFFFULL);
        int n = cand / 10;
        int c = (int)(cand - n * 10) + 1;
        int r = b * NPROP + n;
        float x1, y1, x2, y2;
        decode4(proposals + (size_t)r * 9, logreg + (size_t)r * LRLD + 11 + c * 9,
                x1, y1, x2, y2);
        int sup = 0;
        for (int q = tid; q < kc; q += 64) {
            if (kcls[q] == c) {
                float xx1 = fmaxf(x1, kbox[q][0]);
                float yy1 = fmaxf(y1, kbox[q][1]);
                float xx2 = fminf(x2, kbox[q][2]);
                float yy2 = fminf(y2, kbox[q][3]);
                float inter = fmaxf(xx2 - xx1, 0.f) * fmaxf(yy2 - yy1, 0.f);
                float aa = (kbox[q][2] - kbox[q][0]) * (kbox[q][3] - kbox[q][1]);
                float ab = (x2 - x1) * (y2 - y1);
                float iou = inter / (aa + ab - inter + 1e-9f);
                if (iou > NMS_T) sup = 1;
            }
        }
        if (!__any(sup)) {
            if (tid == 0) {
                kbox[kc][0] = x1; kbox[kc][1] = y1; kbox[kc][2] = x2; kbox[kc][3] = y2;
                kcls[kc] = c; kcand[kc] = (int)cand; kcount = kc + 1;
            }
        }
    }
    __syncthreads();
    int kc = min(kcount, KKEEP);
    for (int k = tid; k < KKEEP; k += 64) {
        int cand = (k < kc) ? kcand[k] : 0;
        int n = cand / 10;
        int c = cand - n * 10 + 1;
        int r = b * NPROP + n;
        const float* prop = proposals + (size_t)r * 9;
        const float* rg = logreg + (size_t)r * LRLD + 11 + c * 9;
        float x1, y1, x2, y2;
        decode4(prop, rg, x1, y1, x2, y2);
        float* ob = out + ((size_t)b * KKEEP + k) * 9;
        ob[0] = x1; ob[1] = y1; ob[2] = x2; ob[3] = y2;
#pragma unroll
        for (int j = 0; j < 5; ++j) ob[4 + j] = prop[4 + j] + rg[4 + j];
        out[NFRAMES * KKEEP * 9 + b * KKEEP + k] =
            (k < kc) ? scores[(size_t)r * 10 + (c - 1)] : 0.f;
        out[NFRAMES * KKEEP * 9 + NFRAMES * KKEEP + b * KKEEP + k] =
            (k < kc) ? (float)c : -1.0f;
    }
}

// ---------------- host launch ----------------
extern "C" void kernel_launch(void* const* d_in, const int* in_sizes, int n_in,
                              void* d_out, int out_size, void* d_ws, size_t ws_size,
                              hipStream_t stream) {
    (void)in_sizes; (void)n_in; (void)out_size;
    if (ws_size < WS_NEEDED) return;

    const float* x         = (const float*)d_in[0];
    const float* proposals = (const float*)d_in[1];
    const float* w1        = (const float*)d_in[2];
    const float* b1        = (const float*)d_in[3];
    const float* w2        = (const float*)d_in[4];
    const float* b2        = (const float*)d_in[5];
    const float* wc        = (const float*)d_in[6];
    const float* bc        = (const float*)d_in[7];
    const float* wr        = (const float*)d_in[8];
    const float* br        = (const float*)d_in[9];
    float* out = (float*)d_out;

    char* ws = (char*)d_ws;
    float* h1     = (float*)(ws + OFF_H1);
    float* h2     = (float*)(ws + OFF_H2);
    float* logreg = (float*)(ws + OFF_LR);
    float* wcat   = (float*)(ws + OFF_WCAT);
    float* bcat   = (float*)(ws + OFF_BCAT);
    float* scores = (float*)(ws + OFF_SCORES);
    int*   hist   = (int*)(ws + OFF_HIST);
    int*   gcount = (int*)(ws + OFF_GCNT);
    int*   taubin = (int*)(ws + OFF_TAU);
    unsigned long long* gkeys = (unsigned long long*)(ws + OFF_GKEYS);

    // zero hist + gcount + taubin (ws is poisoned before every call)
    hipMemsetAsync(hist, 0, (size_t)(NFRAMES * NBINS * 4 + 256), stream);

    concat_w<<<(HDIM * LRLD + 255) / 256, 256, 0, stream>>>(wc, bc, wr, br, wcat, bcat);

    gemm_t16<<<dim3(NROWS / 256, HDIM / 128), 256, 0, stream>>>(x,  w1, b1, h1, DIN_, HDIM, 1);
    gemm_t16<<<dim3(NROWS / 256, HDIM / 128), 256, 0, stream>>>(h1, w2, b2, h2, HDIM, HDIM, 1);
    gemm128 <<<dim3(NROWS / 128, 1),          256, 0, stream>>>(h2, wcat, bcat, logreg, HDIM, LRLD, 0);

    softmax_hist<<<NROWS / 256, 256, 0, stream>>>(logreg, scores, hist);
    select_tau<<<NFRAMES, 1024, 0, stream>>>(hist, taubin);
    gather_cand<<<(NROWS * 10 + 255) / 256, 256, 0, stream>>>(scores, logreg, proposals,
                                                              taubin, gcount, gkeys);
    sort_cand<<<NFRAMES, 1024, 0, stream>>>(gcount, gkeys);
    nms_out<<<NFRAMES, 64, 0, stream>>>(gkeys, gcount, scores, logreg, proposals, out);
}

// Round 5
// 1085.170 us; speedup vs baseline: 1.1134x; 1.1134x over previous
//
#include <hip/hip_runtime.h>
#include <stdint.h>

// ---------------- problem constants ----------------
#define NFRAMES 2
#define NPROP   16384
#define NROWS   (NFRAMES * NPROP)        // 32768
#define DIN_    1024
#define HDIM    512
#define NCLS    11
#define LRLD    128                      // padded cols of [logits(11) | reg(99) | pad]
#define NBINS   8192
#define CAP     2048                     // gathered candidate capacity per frame
#define TGT     1024                     // target top-N for NMS scan (gathered ~= TGT+bin)
#define KKEEP   100
#define SCORE_T 0.05f
#define NMS_T   0.5f
#define CLIPV   4.135166556742356f       // log(1000/16)
#define BK      8

// ---------------- workspace layout (bytes) ----------------
#define OFF_H1      0ULL                           // 32768*512 f32
#define OFF_H2      67108864ULL                    // 32768*512 f32
#define OFF_LR      134217728ULL                   // 32768*128 f32
#define OFF_WCAT    150994944ULL                   // 512*128 f32
#define OFF_BCAT    151257088ULL                   // 128 f32 (padded)
#define OFF_SCORES  151258112ULL                   // 32768*10 f32
#define OFF_HIST    152568832ULL                   // 2*8192 i32
#define OFF_GCNT    152634368ULL                   // 2 i32
#define OFF_TAU     152634376ULL                   // 2 i32
#define OFF_GKEYS   152634624ULL                   // 2*2048 u64
#define WS_NEEDED   152700160ULL

// ---------------- box decode (must match reference float ops) ----------------
__device__ __forceinline__ void decode4(const float* __restrict__ prop,
                                        const float* __restrict__ rg,
                                        float& x1, float& y1, float& x2, float& y2) {
    float w  = prop[2] - prop[0];
    float h  = prop[3] - prop[1];
    float cx = prop[0] + 0.5f * w;
    float cy = prop[1] + 0.5f * h;
    float dx = rg[0] / 10.0f;
    float dy = rg[1] / 10.0f;
    float dw = fminf(rg[2] / 5.0f, CLIPV);
    float dh = fminf(rg[3] / 5.0f, CLIPV);
    float pcx = dx * w + cx;
    float pcy = dy * h + cy;
    float pw  = expf(dw) * w;
    float ph  = expf(dh) * h;
    x1 = pcx - 0.5f * pw;
    y1 = pcy - 0.5f * ph;
    x2 = pcx + 0.5f * pw;
    y2 = pcy + 0.5f * ph;
}

// ---------------- fp32 GEMM, 256x128 tile, 16x8 micro-tile ----------------
// R3 post-mortem: 16x8 acc spilled (VGPR_Count=128 == acc size, WRITE_SIZE 210MB
// = 64MB C + 146MB scratch). R4: pin occupancy to exactly 2 waves/EU (budget 256
// VGPR) via amdgpu_waves_per_eu(2,2), and consume A float4s immediately per 4-row
// chunk (no ar[16]/br[8] staging arrays) -> peak live ~175 regs, spill-free.
// LDS-BW model: 6 b128 / 128 FMA = 0.75 B/FMA -> predicted ~88% VALU bound
// (8x8 was 1 B/FMA -> 66%, matched R1/R2 measurements exactly).
__global__ __launch_bounds__(256, 2)
__attribute__((amdgpu_waves_per_eu(2, 2)))
void gemm_t16(const float* __restrict__ A,
              const float* __restrict__ B,
              const float* __restrict__ bias,
              float* __restrict__ C,
              int K, int N, int do_relu) {
    __shared__ float As[BK][256];   // k-major, 8 KB
    __shared__ float Bs[BK][128];   // 4 KB
    const int tid  = threadIdx.x;
    const int row0 = blockIdx.x * 256;
    const int col0 = blockIdx.y * 128;
    const int tx4  = (tid & 15) * 4;        // col offsets tx4 and 64+tx4
    const int rg16 = (tid >> 4) * 16;       // 16 consecutive rows

    const int bkr = tid >> 5;               // 0..7
    const int bc4 = (tid & 31) * 4;         // 0..124
    const float* Ap = A + (size_t)(row0 + tid) * K;
    const float* Bp = B + (size_t)bkr * N + col0 + bc4;

    float acc[16][8];
#pragma unroll
    for (int i = 0; i < 16; ++i)
#pragma unroll
        for (int j = 0; j < 8; ++j) acc[i][j] = 0.f;

    // prologue: stage 0
    float4 pa0 = *(const float4*)(Ap + 0);
    float4 pa1 = *(const float4*)(Ap + 4);
    float4 pb  = *(const float4*)(Bp);
    As[0][tid] = pa0.x; As[1][tid] = pa0.y; As[2][tid] = pa0.z; As[3][tid] = pa0.w;
    As[4][tid] = pa1.x; As[5][tid] = pa1.y; As[6][tid] = pa1.z; As[7][tid] = pa1.w;
    *(float4*)&Bs[bkr][bc4] = pb;
    __syncthreads();

    for (int k0 = 0; k0 < K; k0 += BK) {
        const bool has_next = (k0 + BK) < K;
        if (has_next) {   // prefetch next stage; consumed after 8*128 FMAs
            pa0 = *(const float4*)(Ap + k0 + BK);
            pa1 = *(const float4*)(Ap + k0 + BK + 4);
            pb  = *(const float4*)(Bp + (size_t)(k0 + BK) * N);
        }
#pragma unroll
        for (int kk = 0; kk < BK; ++kk) {
            float4 b0 = *(const float4*)&Bs[kk][tx4];
            float4 b1 = *(const float4*)&Bs[kk][64 + tx4];
#pragma unroll
            for (int ch = 0; ch < 4; ++ch) {
                float4 a4 = *(const float4*)&As[kk][rg16 + ch * 4];
                const int r = ch * 4;
                acc[r+0][0] += a4.x*b0.x; acc[r+0][1] += a4.x*b0.y;
                acc[r+0][2] += a4.x*b0.z; acc[r+0][3] += a4.x*b0.w;
                acc[r+0][4] += a4.x*b1.x; acc[r+0][5] += a4.x*b1.y;
                acc[r+0][6] += a4.x*b1.z; acc[r+0][7] += a4.x*b1.w;
                acc[r+1][0] += a4.y*b0.x; acc[r+1][1] += a4.y*b0.y;
                acc[r+1][2] += a4.y*b0.z; acc[r+1][3] += a4.y*b0.w;
                acc[r+1][4] += a4.y*b1.x; acc[r+1][5] += a4.y*b1.y;
                acc[r+1][6] += a4.y*b1.z; acc[r+1][7] += a4.y*b1.w;
                acc[r+2][0] += a4.z*b0.x; acc[r+2][1] += a4.z*b0.y;
                acc[r+2][2] += a4.z*b0.z; acc[r+2][3] += a4.z*b0.w;
                acc[r+2][4] += a4.z*b1.x; acc[r+2][5] += a4.z*b1.y;
                acc[r+2][6] += a4.z*b1.z; acc[r+2][7] += a4.z*b1.w;
                acc[r+3][0] += a4.w*b0.x; acc[r+3][1] += a4.w*b0.y;
                acc[r+3][2] += a4.w*b0.z; acc[r+3][3] += a4.w*b0.w;
                acc[r+3][4] += a4.w*b1.x; acc[r+3][5] += a4.w*b1.y;
                acc[r+3][6] += a4.w*b1.z; acc[r+3][7] += a4.w*b1.w;
            }
        }
        if (has_next) {
            __syncthreads();   // all reads of current buffer done
            As[0][tid] = pa0.x; As[1][tid] = pa0.y; As[2][tid] = pa0.z; As[3][tid] = pa0.w;
            As[4][tid] = pa1.x; As[5][tid] = pa1.y; As[6][tid] = pa1.z; As[7][tid] = pa1.w;
            *(float4*)&Bs[bkr][bc4] = pb;
            __syncthreads();   // writes visible
        }
    }

    float4 bias_lo = *(const float4*)&bias[col0 + tx4];
    float4 bias_hi = *(const float4*)&bias[col0 + 64 + tx4];
#pragma unroll
    for (int i = 0; i < 16; ++i) {
        int row = row0 + rg16 + i;
        float4 v;
        v.x = acc[i][0] + bias_lo.x; v.y = acc[i][1] + bias_lo.y;
        v.z = acc[i][2] + bias_lo.z; v.w = acc[i][3] + bias_lo.w;
        if (do_relu) {
            v.x = fmaxf(v.x, 0.f); v.y = fmaxf(v.y, 0.f);
            v.z = fmaxf(v.z, 0.f); v.w = fmaxf(v.w, 0.f);
        }
        *(float4*)(C + (size_t)row * N + col0 + tx4) = v;
        v.x = acc[i][4] + bias_hi.x; v.y = acc[i][5] + bias_hi.y;
        v.z = acc[i][6] + bias_hi.z; v.w = acc[i][7] + bias_hi.w;
        if (do_relu) {
            v.x = fmaxf(v.x, 0.f); v.y = fmaxf(v.y, 0.f);
            v.z = fmaxf(v.z, 0.f); v.w = fmaxf(v.w, 0.f);
        }
        *(float4*)(C + (size_t)row * N + col0 + 64 + tx4) = v;
    }
}

// ---------------- fp32 GEMM 128x128, 8x8/thread (R1 version, for gemm3 N=128) ----------------
__global__ __launch_bounds__(256) void gemm128(const float* __restrict__ A,
                                               const float* __restrict__ B,
                                               const float* __restrict__ bias,
                                               float* __restrict__ C,
                                               int K, int N, int do_relu) {
    __shared__ float As[8][128];
    __shared__ float Bs[8][128];
    const int tid  = threadIdx.x;
    const int row0 = blockIdx.x * 128;
    const int col0 = blockIdx.y * 128;
    const int tx = tid & 15, ty = tid >> 4;

    float acc[8][8];
#pragma unroll
    for (int i = 0; i < 8; ++i)
#pragma unroll
        for (int j = 0; j < 8; ++j) acc[i][j] = 0.f;

    const int arow  = tid >> 1;
    const int akoff = (tid & 1) * 4;
    const int bkrow = tid >> 5;
    const int bcol  = (tid & 31) * 4;
    const float* Ap = A + (size_t)(row0 + arow) * K + akoff;
    const float* Bp = B + (size_t)bkrow * N + col0 + bcol;

    for (int k0 = 0; k0 < K; k0 += 8) {
        float4 av = *(const float4*)(Ap + k0);
        float4 bv = *(const float4*)(Bp + (size_t)k0 * N);
        __syncthreads();
        As[akoff + 0][arow] = av.x;
        As[akoff + 1][arow] = av.y;
        As[akoff + 2][arow] = av.z;
        As[akoff + 3][arow] = av.w;
        *(float4*)&Bs[bkrow][bcol] = bv;
        __syncthreads();
#pragma unroll
        for (int kk = 0; kk < 8; ++kk) {
            float4 a0 = *(const float4*)&As[kk][ty * 4];
            float4 a1 = *(const float4*)&As[kk][64 + ty * 4];
            float4 b0 = *(const float4*)&Bs[kk][tx * 4];
            float4 b1 = *(const float4*)&Bs[kk][64 + tx * 4];
            float ar[8] = {a0.x, a0.y, a0.z, a0.w, a1.x, a1.y, a1.z, a1.w};
            float br[8] = {b0.x, b0.y, b0.z, b0.w, b1.x, b1.y, b1.z, b1.w};
#pragma unroll
            for (int i = 0; i < 8; ++i)
#pragma unroll
                for (int j = 0; j < 8; ++j) acc[i][j] += ar[i] * br[j];
        }
    }

#pragma unroll
    for (int qi = 0; qi < 2; ++qi)
#pragma unroll
        for (int i = 0; i < 4; ++i) {
            int row = row0 + qi * 64 + ty * 4 + i;
#pragma unroll
            for (int qj = 0; qj < 2; ++qj) {
                int col = col0 + qj * 64 + tx * 4;
                float4 v;
                v.x = acc[qi * 4 + i][qj * 4 + 0] + bias[col + 0];
                v.y = acc[qi * 4 + i][qj * 4 + 1] + bias[col + 1];
                v.z = acc[qi * 4 + i][qj * 4 + 2] + bias[col + 2];
                v.w = acc[qi * 4 + i][qj * 4 + 3] + bias[col + 3];
                if (do_relu) {
                    v.x = fmaxf(v.x, 0.f); v.y = fmaxf(v.y, 0.f);
                    v.z = fmaxf(v.z, 0.f); v.w = fmaxf(v.w, 0.f);
                }
                *(float4*)(C + (size_t)row * N + col) = v;
            }
        }
}

// ---------------- concat wc|wr into [512][128] + zero hist/gcount/tau ----------------
// R4: absorbs the hipMemsetAsync (one fewer dispatch).
__global__ void concat_w(const float* __restrict__ wc, const float* __restrict__ bc,
                         const float* __restrict__ wr, const float* __restrict__ br,
                         float* __restrict__ wcat, float* __restrict__ bcat,
                         int* __restrict__ hist, int* __restrict__ gcnt4) {
    int gid = blockIdx.x * 256 + threadIdx.x;
    if (gid >= HDIM * LRLD) return;
    if (gid < NFRAMES * NBINS) hist[gid] = 0;
    if (gid < 4) gcnt4[gid] = 0;          // gcount[2] + taubin[2] (contiguous)
    int k = gid >> 7, j = gid & 127;
    float v = 0.f;
    if (j < 11)       v = wc[k * 11 + j];
    else if (j < 110) v = wr[k * 99 + (j - 11)];
    wcat[gid] = v;
    if (k == 0) {
        float b = 0.f;
        if (j < 11)       b = bc[j];
        else if (j < 110) b = br[j - 11];
        bcat[j] = b;
    }
}

// ---------------- softmax + score histogram ----------------
__global__ __launch_bounds__(256) void softmax_hist(const float* __restrict__ logreg,
                                                    float* __restrict__ scores,
                                                    int* __restrict__ hist) {
    __shared__ int lh[NBINS];   // 32 KB
    const int t = threadIdx.x;
    for (int i = t; i < NBINS; i += 256) lh[i] = 0;
    __syncthreads();

    const int r = blockIdx.x * 256 + t;
    const float* lr = logreg + (size_t)r * LRLD;
    float4 v0 = *(const float4*)(lr);
    float4 v1 = *(const float4*)(lr + 4);
    float4 v2 = *(const float4*)(lr + 8);
    float l[NCLS] = {v0.x, v0.y, v0.z, v0.w, v1.x, v1.y, v1.z, v1.w, v2.x, v2.y, v2.z};
    float m = l[0];
#pragma unroll
    for (int j = 1; j < NCLS; ++j) m = fmaxf(m, l[j]);
    float e[NCLS]; float s = 0.f;
#pragma unroll
    for (int j = 0; j < NCLS; ++j) { e[j] = expf(l[j] - m); s += e[j]; }
#pragma unroll
    for (int c = 1; c < NCLS; ++c) {
        float p = e[c] / s;
        scores[(size_t)r * 10 + (c - 1)] = p;
        if (p > SCORE_T) {
            int bin = (int)(p * (float)NBINS);
            bin = min(max(bin, 0), NBINS - 1);
            atomicAdd(&lh[bin], 1);
        }
    }
    __syncthreads();
    const int b = (blockIdx.x * 256) >> 14;
    for (int i = t; i < NBINS; i += 256) {
        int c = lh[i];
        if (c) atomicAdd(&hist[b * NBINS + i], c);
    }
}

// ---------------- find histogram bin threshold covering top >= TGT ----------------
__global__ __launch_bounds__(1024) void select_tau(const int* __restrict__ hist,
                                                   int* __restrict__ taubin) {
    __shared__ int seg[1024];
    __shared__ int best;
    const int b = blockIdx.x, t = threadIdx.x;
    if (t == 0) best = 0;
    const int base = t * 8;
    int loc[8];
    int s = 0;
#pragma unroll
    for (int i = 7; i >= 0; --i) {
        s += hist[b * NBINS + base + i];
        loc[i] = s;
    }
    seg[t] = s;
    __syncthreads();
    for (int off = 1; off < 1024; off <<= 1) {
        int v = (t + off < 1024) ? seg[t + off] : 0;
        __syncthreads();
        seg[t] += v;
        __syncthreads();
    }
    const int above = (t + 1 < 1024) ? seg[t + 1] : 0;
    int bmax = -1;
#pragma unroll
    for (int i = 0; i < 8; ++i) {
        if (loc[i] + above >= TGT) bmax = base + i;
    }
    if (bmax >= 0) atomicMax(&best, bmax);
    __syncthreads();
    if (t == 0) taubin[b] = best;
}

// ---------------- gather top candidates as sortable keys ----------------
__global__ void gather_cand(const float* __restrict__ scores,
                            const float* __restrict__ logreg,
                            const float* __restrict__ proposals,
                            const int* __restrict__ taubin,
                            int* __restrict__ gcount,
                            unsigned long long* __restrict__ gkeys) {
    int gid = blockIdx.x * 256 + threadIdx.x;
    if (gid >= NROWS * 10) return;
    int r  = gid / 10;
    int ci = gid - r * 10;          // class-1
    int b  = r >> 14;
    float p = scores[gid];
    int bin = (int)(p * (float)NBINS);
    bin = min(max(bin, 0), NBINS - 1);
    if (bin < taubin[b]) return;
    if (!(p > SCORE_T)) return;
    float x1, y1, x2, y2;
    decode4(proposals + (size_t)r * 9, logreg + (size_t)r * LRLD + 11 + (ci + 1) * 9,
            x1, y1, x2, y2);
    if (!((x2 - x1) >= 0.01f && (y2 - y1) >= 0.01f)) return;
    int pos = atomicAdd(&gcount[b], 1);
    if (pos < CAP) {
        unsigned int sb   = __float_as_uint(p);                 // p > 0 => order-preserving
        unsigned int cand = (unsigned)(r - b * NPROP) * 10u + (unsigned)ci;
        gkeys[(size_t)b * CAP + pos] =
            ((unsigned long long)(0xFFFFFFFFu - sb) << 32) | (unsigned long long)cand;
    }
}

// ---------------- bitonic sort of CAP keys per frame ----------------
__global__ __launch_bounds__(1024) void sort_cand(int* __restrict__ gcount,
                                                  unsigned long long* __restrict__ gkeys) {
    __shared__ unsigned long long sk[CAP];
    int b = blockIdx.x, tid = threadIdx.x;
    int gc = gcount[b]; if (gc > CAP) gc = CAP;
    for (int i = tid; i < CAP; i += 1024)
        sk[i] = (i < gc) ? gkeys[(size_t)b * CAP + i] : ~0ULL;
    __syncthreads();
    for (int k = 2; k <= CAP; k <<= 1) {
        for (int j = k >> 1; j > 0; j >>= 1) {
            for (int i = tid; i < CAP; i += 1024) {
                int ixj = i ^ j;
                if (ixj > i) {
                    bool up = ((i & k) == 0);
                    unsigned long long a = sk[i], c = sk[ixj];
                    if ((a > c) == up) { sk[i] = c; sk[ixj] = a; }
                }
            }
            __syncthreads();
        }
    }
    for (int i = tid; i < CAP; i += 1024)
        gkeys[(size_t)b * CAP + i] = sk[i];
    if (tid == 0 && gcount[b] > CAP) gcount[b] = CAP;
}

// ---------------- serial greedy NMS scan + output ----------------
__global__ __launch_bounds__(64) void nms_out(const unsigned long long* __restrict__ gkeys,
                                              const int* __restrict__ gcount,
                                              const float* __restrict__ scores,
                                              const float* __restrict__ logreg,
                                              const float* __restrict__ proposals,
                                              float* __restrict__ out) {
    int b = blockIdx.x, tid = threadIdx.x;
    __shared__ unsigned long long skeys[CAP];   // 16 KB: covers entire sorted list
    __shared__ float kbox[KKEEP][4];
    __shared__ int   kcls[KKEEP];
    __shared__ int   kcand[KKEEP];
    __shared__ int   kcount;
    if (tid == 0) kcount = 0;
    int gc = min(gcount[b], CAP);
    for (int i = tid; i < gc; i += 64)
        skeys[i] = gkeys[(size_t)b * CAP + i];
    __syncthreads();
    for (int ptr = 0; ptr < gc; ++ptr) {
        __syncthreads();
        int kc = kcount;
        if (kc >= KKEEP) break;
        unsigned long long key = skeys[ptr];
        unsigned int cand = (unsigned int)(key & 0xFFFFFFFFULL);
        int n = cand / 10;
        int c = (int)(cand - n * 10) + 1;
        int r = b * NPROP + n;
        float x1, y1, x2, y2;
        decode4(proposals + (size_t)r * 9, logreg + (size_t)r * LRLD + 11 + c * 9,
                x1, y1, x2, y2);
        int sup = 0;
        for (int q = tid; q < kc; q += 64) {
            if (kcls[q] == c) {
                float xx1 = fmaxf(x1, kbox[q][0]);
                float yy1 = fmaxf(y1, kbox[q][1]);
                float xx2 = fminf(x2, kbox[q][2]);
                float yy2 = fminf(y2, kbox[q][3]);
                float inter = fmaxf(xx2 - xx1, 0.f) * fmaxf(yy2 - yy1, 0.f);
                float aa = (kbox[q][2] - kbox[q][0]) * (kbox[q][3] - kbox[q][1]);
                float ab = (x2 - x1) * (y2 - y1);
                float iou = inter / (aa + ab - inter + 1e-9f);
                if (iou > NMS_T) sup = 1;
            }
        }
        if (!__any(sup)) {
            if (tid == 0) {
                kbox[kc][0] = x1; kbox[kc][1] = y1; kbox[kc][2] = x2; kbox[kc][3] = y2;
                kcls[kc] = c; kcand[kc] = (int)cand; kcount = kc + 1;
            }
        }
    }
    __syncthreads();
    int kc = min(kcount, KKEEP);
    for (int k = tid; k < KKEEP; k += 64) {
        int cand = (k < kc) ? kcand[k] : 0;
        int n = cand / 10;
        int c = cand - n * 10 + 1;
        int r = b * NPROP + n;
        const float* prop = proposals + (size_t)r * 9;
        const float* rg = logreg + (size_t)r * LRLD + 11 + c * 9;
        float x1, y1, x2, y2;
        decode4(prop, rg, x1, y1, x2, y2);
        float* ob = out + ((size_t)b * KKEEP + k) * 9;
        ob[0] = x1; ob[1] = y1; ob[2] = x2; ob[3] = y2;
#pragma unroll
        for (int j = 0; j < 5; ++j) ob[4 + j] = prop[4 + j] + rg[4 + j];
        out[NFRAMES * KKEEP * 9 + b * KKEEP + k] =
            (k < kc) ? scores[(size_t)r * 10 + (c - 1)] : 0.f;
        out[NFRAMES * KKEEP * 9 + NFRAMES * KKEEP + b * KKEEP + k] =
            (k < kc) ? (float)c : -1.0f;
    }
}

// ---------------- host launch ----------------
extern "C" void kernel_launch(void* const* d_in, const int* in_sizes, int n_in,
                              void* d_out, int out_size, void* d_ws, size_t ws_size,
                              hipStream_t stream) {
    (void)in_sizes; (void)n_in; (void)out_size;
    if (ws_size < WS_NEEDED) return;

    const float* x         = (const float*)d_in[0];
    const float* proposals = (const float*)d_in[1];
    const float* w1        = (const float*)d_in[2];
    const float* b1        = (const float*)d_in[3];
    const float* w2        = (const float*)d_in[4];
    const float* b2        = (const float*)d_in[5];
    const float* wc        = (const float*)d_in[6];
    const float* bc        = (const float*)d_in[7];
    const float* wr        = (const float*)d_in[8];
    const float* br        = (const float*)d_in[9];
    float* out = (float*)d_out;

    char* ws = (char*)d_ws;
    float* h1     = (float*)(ws + OFF_H1);
    float* h2     = (float*)(ws + OFF_H2);
    float* logreg = (float*)(ws + OFF_LR);
    float* wcat   = (float*)(ws + OFF_WCAT);
    float* bcat   = (float*)(ws + OFF_BCAT);
    float* scores = (float*)(ws + OFF_SCORES);
    int*   hist   = (int*)(ws + OFF_HIST);
    int*   gcount = (int*)(ws + OFF_GCNT);
    int*   taubin = (int*)(ws + OFF_TAU);
    unsigned long long* gkeys = (unsigned long long*)(ws + OFF_GKEYS);

    concat_w<<<(HDIM * LRLD + 255) / 256, 256, 0, stream>>>(wc, bc, wr, br, wcat, bcat,
                                                            hist, gcount);

    gemm_t16<<<dim3(NROWS / 256, HDIM / 128), 256, 0, stream>>>(x,  w1, b1, h1, DIN_, HDIM, 1);
    gemm_t16<<<dim3(NROWS / 256, HDIM / 128), 256, 0, stream>>>(h1, w2, b2, h2, HDIM, HDIM, 1);
    gemm128 <<<dim3(NROWS / 128, 1),          256, 0, stream>>>(h2, wcat, bcat, logreg, HDIM, LRLD, 0);

    softmax_hist<<<NROWS / 256, 256, 0, stream>>>(logreg, scores, hist);
    select_tau<<<NFRAMES, 1024, 0, stream>>>(hist, taubin);
    gather_cand<<<(NROWS * 10 + 255) / 256, 256, 0, stream>>>(scores, logreg, proposals,
                                                              taubin, gcount, gkeys);
    sort_cand<<<NFRAMES, 1024, 0, stream>>>(gcount, gkeys);
    nms_out<<<NFRAMES, 64, 0, stream>>>(gkeys, gcount, scores, logreg, proposals, out);
}